// Round 17
// baseline (178.904 us; speedup 1.0000x reference)
//
#include <hip/hip_runtime.h>
#include <hip/hip_bf16.h>
#include <math.h>

// GAT forward, N=4096, nfeat=512, nhid=64, nheads=8, nout=56, f32 in/out.
// R32 vs R31/R29 (R29 175.7 BEST no-remap; R31 178.1 with remap at 2blk/CU
// -- remap's FETCH cut (18->10.4MB, R30-verified) buys no TIME at proper
// occupancy => stage loads already hidden; REVERTED).
// New mechanism: attn-L1's own 16MB pO WRITE stream is what evicts the
// 4MB images from each XCD L2 (write-allocate thrash). pO is write-once/
// read-once (mid, fink2 stream it) -- zero reuse value in L2.
//  - attn15: pO stores via __builtin_nontemporal_store (bypass L2; values
//    bit-identical). Applied to both L1 and L2 dispatches.
//  - Everything else exactly R29: attn-L1 NCHUNK=2 standard mapping,
//    attn-L2 NCHUNK=8, fink2<8>, prep grid-stride 2624, gemm 2-kt-phase,
//    mid 2-slice combine.

#define GN 4096
#define GNH 8
#define LOG2E 1.4426950408889634f

typedef _Float16 f16x8 __attribute__((ext_vector_type(8)));
typedef _Float16 f16x2 __attribute__((ext_vector_type(2)));
typedef __fp16 fp16x2_raw __attribute__((ext_vector_type(2)));
typedef float f32x4 __attribute__((ext_vector_type(4)));

#if defined(__has_builtin)
#if __has_builtin(__builtin_amdgcn_exp2f)
#define FAST_EXP2(x) __builtin_amdgcn_exp2f(x)
#endif
#if __has_builtin(__builtin_amdgcn_perm)
#define MASK_PERM(h, l) __builtin_amdgcn_perm((h), (l), 0x05040100u)
#endif
#if __has_builtin(__builtin_amdgcn_cvt_pkrtz)
#define HAVE_PKRTZ 1
#endif
#endif
#ifndef FAST_EXP2
#define FAST_EXP2(x) __expf((x)*0.6931471805599453f)
#endif
#ifndef MASK_PERM
#define MASK_PERM(h, l) (((h) & 0xFFFF0000u) | ((l) & 0xFFFFu))
#endif

// pack two floats to fp16 pair (a in low 16, b in high 16)
__device__ inline unsigned pk_f16(float a, float b) {
#ifdef HAVE_PKRTZ
    union { fp16x2_raw h; unsigned u; } r;
    r.h = __builtin_amdgcn_cvt_pkrtz(a, b);
    return r.u;
#else
    union { _Float16 h; unsigned short s; } x, y;
    x.h = (_Float16)a; y.h = (_Float16)b;
    return (unsigned)x.s | ((unsigned)y.s << 16);
#endif
}

// Fused prep (grid-stride, 2624 blocks):
//  [0,2048)      pack_adj  x8 iters (bitmask)
//  [2048,2560)   conv_x    x2 iters -> swizzled x image (fp16)
//  [2560,2624)   conv_wt   -> swizzled W^T image (fp16), tiles [head*8+kt]
// Image unit (m, c) at shorts offset m*64 + ((c^(m&7))*8), elems k = c*8+q.
__global__ __launch_bounds__(256) void prep(const int* __restrict__ adj,
                                            const float* __restrict__ x,
                                            const float* __restrict__ Ws,
                                            unsigned long long* __restrict__ adjb,
                                            unsigned short* __restrict__ xh,
                                            unsigned short* __restrict__ wth) {
    const int b = blockIdx.x;
    const int tid = threadIdx.x;
    if (b < 2048) {
        const int wv = tid >> 6, lane = tid & 63;
        #pragma unroll 1
        for (int it = 0; it < 8; ++it) {
            const int ob = b * 8 + it;
            const size_t ebase = ((size_t)ob * 4 + wv) * 256;
            unsigned long long m[4];
            #pragma unroll
            for (int e = 0; e < 4; ++e)
                m[e] = __ballot(adj[ebase + e * 64 + lane] > 0);
            if (lane == 0) {
                #pragma unroll
                for (int e = 0; e < 4; ++e) adjb[(ebase >> 6) + e] = m[e];
            }
        }
    } else if (b < 2560) {
        #pragma unroll 1
        for (int it = 0; it < 2; ++it) {
            int gid = ((b - 2048) * 2 + it) * 256 + tid;  // over 4096 rows x 64 units
            int i = gid >> 6, c64 = gid & 63;
            const float* xp = x + (size_t)i * 512 + c64 * 8;
            float4 a = *(const float4*)xp;
            float4 v = *(const float4*)(xp + 4);
            unsigned hp[4];
            hp[0] = pk_f16(a.x, a.y);
            hp[1] = pk_f16(a.z, a.w);
            hp[2] = pk_f16(v.x, v.y);
            hp[3] = pk_f16(v.z, v.w);
            int il = i & 63, kt = c64 >> 3, c = c64 & 7;
            size_t base = ((size_t)(i >> 6) * 8 + kt) * 4096 + il * 64 + ((c ^ (il & 7)) * 8);
            *(uint4*)&xh[base] = *(uint4*)hp;
        }
    } else {
        __shared__ float t[64][65];
        int b2 = b - 2560;                           // head*8 + kt
        int head = b2 >> 3, k0 = (b2 & 7) * 64;
        #pragma unroll
        for (int it = 0; it < 4; ++it) {
            int e = (tid + it * 256) * 4;            // over 64k x 64f
            int kl = e >> 6, f4 = e & 63;
            float4 v = *(const float4*)&Ws[((size_t)head * 512 + k0 + kl) * 64 + f4];
            t[f4 + 0][kl] = v.x; t[f4 + 1][kl] = v.y;
            t[f4 + 2][kl] = v.z; t[f4 + 3][kl] = v.w;
        }
        __syncthreads();
        int f = tid >> 2;
        #pragma unroll
        for (int p = 0; p < 2; ++p) {
            int c = (tid & 3) * 2 + p;
            unsigned hp[4];
            #pragma unroll
            for (int pp = 0; pp < 4; ++pp)
                hp[pp] = pk_f16(t[f][c * 8 + 2 * pp], t[f][c * 8 + 2 * pp + 1]);
            size_t base = (size_t)b2 * 4096 + f * 64 + ((c ^ (f & 7)) * 8);
            *(uint4*)&wth[base] = *(uint4*)hp;
        }
    }
}

// h = x @ W (single fp16 product). TWO k-tiles per barrier phase
// (4 phases), lds = 2 bufs x 2 kt x {x,w} x 8KB = 64 KB, 2 blk/CU.
// Epilogue emits fp16 swizzled h image + per-row softmax factors:
// rL = exp(.8*s1) f32; ebL = packed fp16 pairs {B_{2j},B_{2j+1}},{b_..}.
// grid (8 heads, 64 itiles).
__global__ __launch_bounds__(256, 2) void gemm_fused(const unsigned short* __restrict__ xh,
                                                     const unsigned short* __restrict__ wth,
                                                     const float* __restrict__ As,
                                                     unsigned short* __restrict__ imgh,
                                                     float* __restrict__ rL,
                                                     uint2* __restrict__ ebL) {
    __shared__ __align__(16) unsigned short lds[2][2][2][4096];  // 64 KB: [buf][kt][x,w]
    const int tid = threadIdx.x;
    const int head = blockIdx.x;
    const int itile = blockIdx.y;
    const int i0 = itile * 64;
    const unsigned short* srcs[2] = {xh + (size_t)itile * 8 * 4096,
                                     wth + (size_t)head * 8 * 4096};
    const int lane = tid & 63, wv_ = tid >> 6;
    const int mi = (wv_ & 1) * 32, fi = (wv_ >> 1) * 32;
    const int row = lane & 15, quad = lane >> 4;
    f32x4 acc[2][2] = {};

    // stage k-tiles 2*kp and 2*kp+1 (both operands) into lds[buf]
    #define GSTAGE2(buf, kp)                                                               \
        do {                                                                               \
            _Pragma("unroll")                                                              \
            for (int tk_ = 0; tk_ < 2; ++tk_) {                                            \
                _Pragma("unroll")                                                          \
                for (int q_ = 0; q_ < 2; ++q_) {                                           \
                    const unsigned short* s_ = srcs[q_] + (size_t)((kp) * 2 + tk_) * 4096; \
                    _Pragma("unroll")                                                      \
                    for (int c_ = 0; c_ < 2; ++c_)                                         \
                        __builtin_amdgcn_global_load_lds(                                  \
                            (const __attribute__((address_space(1))) unsigned int*)(s_ + c_ * 2048 + tid * 8), \
                            (__attribute__((address_space(3))) unsigned int*)&lds[buf][tk_][q_][c_ * 2048 + tid * 8], \
                            16, 0, 0);                                                     \
                }                                                                          \
            }                                                                              \
        } while (0)

    GSTAGE2(0, 0);
    for (int kp = 0; kp < 4; ++kp) {
        __syncthreads();                             // drains loads into buf cur
        const int cur = kp & 1;
        if (kp + 1 < 4) GSTAGE2(cur ^ 1, kp + 1);
        #pragma unroll
        for (int tki = 0; tki < 2; ++tki) {
            #pragma unroll
            for (int ks = 0; ks < 2; ++ks) {
                f16x8 ah[2], bh[2];
                #pragma unroll
                for (int t = 0; t < 2; ++t) {
                    const int m_ = mi + t * 16 + row;
                    const int offa = m_ * 64 + (((ks * 4 + quad) ^ (m_ & 7)) * 8);
                    ah[t] = *(const f16x8*)&lds[cur][tki][0][offa];
                    const int f_ = fi + t * 16 + row;
                    const int offb = f_ * 64 + (((ks * 4 + quad) ^ (f_ & 7)) * 8);
                    bh[t] = *(const f16x8*)&lds[cur][tki][1][offb];
                }
                #pragma unroll
                for (int mt = 0; mt < 2; ++mt)
                    #pragma unroll
                    for (int nt = 0; nt < 2; ++nt)
                        acc[mt][nt] = __builtin_amdgcn_mfma_f32_16x16x32_f16(ah[mt], bh[nt], acc[mt][nt], 0, 0, 0);
            }
        }
    }
    #undef GSTAGE2
    // ---- fused epilogue ----
    __syncthreads();
    float* ht = (float*)&lds[0][0][0][0];            // 64 x 68 f32 (17.4 KB <= 64 KB)
    #pragma unroll
    for (int mt = 0; mt < 2; ++mt)
        #pragma unroll
        for (int nt = 0; nt < 2; ++nt)
            #pragma unroll
            for (int r = 0; r < 4; ++r)
                ht[(mi + mt * 16 + quad * 4 + r) * 68 + fi + nt * 16 + row] = acc[mt][nt][r];
    __syncthreads();
    {   // s1/s2 -> row factors: thread t -> row t>>2, seg (t&3)*16
        const int rrow = tid >> 2, seg = (tid & 3) * 16;
        const float* ah = As + head * 128;
        float p1 = 0.f, p2 = 0.f;
        #pragma unroll
        for (int c = 0; c < 16; ++c) {
            float v = ht[rrow * 68 + seg + c];
            p1 += v * ah[seg + c];
            p2 += v * ah[64 + seg + c];
        }
        p1 += __shfl_xor(p1, 1); p1 += __shfl_xor(p1, 2);
        p2 += __shfl_xor(p2, 1); p2 += __shfl_xor(p2, 2);
        // all lanes now hold full p1,p2 for row rrow
        const float r_ = FAST_EXP2(0.8f * p1 * LOG2E);
        const float B_ = FAST_EXP2(p2 * LOG2E);
        const float b_ = FAST_EXP2(0.2f * p2 * LOG2E);
        const float Bo = __shfl_xor(B_, 4);          // row rrow^1's B
        const float bo = __shfl_xor(b_, 4);
        const int gi = i0 + rrow;
        if ((tid & 3) == 0) rL[head * GN + gi] = r_;
        if ((tid & 7) == 0) {                        // even rrow writes the pair
            uint2 e;
            e.x = pk_f16(B_, Bo);
            e.y = pk_f16(b_, bo);
            ebL[head * (GN / 2) + (gi >> 1)] = e;
        }
    }
    {   // swizzled image emit (fp16)
        const int f = tid >> 2;
        size_t base = ((size_t)head * 64 + itile) * 4096 + (size_t)f * 64;
        #pragma unroll
        for (int p = 0; p < 2; ++p) {
            int c = (tid & 3) * 2 + p;
            unsigned hp[4];
            #pragma unroll
            for (int pp = 0; pp < 4; ++pp)
                hp[pp] = pk_f16(ht[(c * 8 + 2 * pp) * 68 + f], ht[(c * 8 + 2 * pp + 1) * 68 + f]);
            int off = (c ^ (f & 7)) * 8;
            *(uint4*)&imgh[base + off] = *(uint4*)hp;
        }
    }
}

// Fused masked-softmax attention, MULTIPLICATIVE fp16-packed weights:
// w'_pair = pk_max(pk_mul(rv2, B2), b2) & signext-bit-mask; den = ones-MFMA
// on the SAME packed values. 4 waves x 2 ROW-GROUPS x 16 rows = 128
// rows/block; FOUR j-tiles per barrier phase (hb = 2 bufs x 4 tiles =
// 64 KB; 2 blk/CU). s_setprio(1) around each tile's MFMA cluster.
// R32: pO stores NON-TEMPORAL (write-once stream; keep images L2-resident).
// grid (32, GNH*NCHUNK) or (32, NCHUNK) for L2.
template <int NCHUNK>
__global__ __launch_bounds__(256, 2) void attn15(const unsigned short* __restrict__ imgh,
                                                 const float* __restrict__ rg,
                                                 const uint2* __restrict__ ebg,
                                                 const unsigned long long* __restrict__ adjb,
                                                 float* __restrict__ pO,
                                                 float* __restrict__ pd) {
    __shared__ __align__(16) unsigned short hb[2][16384];  // 64 KB: [buf][4 tiles]
    const int tid = threadIdx.x;
    const int lane = tid & 63, wv = tid >> 6;              // wv in [0,4)
    const int row = lane & 15, quad = lane >> 4;
    const int head = blockIdx.y / NCHUNK;
    const int chunk = blockIdx.y % NCHUNK;
    const int ib = blockIdx.x;
    const int slice = blockIdx.y;
    const int i0 = ib * 128;                               // 128 rows/block
    const int jb = chunk * (GN / NCHUNK);
    const int njt = (GN / NCHUNK) / 64;
    const int njp4 = njt >> 2;                       // 4 tiles per phase
    const int jt0 = jb >> 6;
    const unsigned short* ih = imgh + (size_t)head * (64 * GN);
    const int gr0 = i0 + wv * 16 + row;                    // group 0 row
    const int gr1 = gr0 + 64;                              // group 1 row
    const float rv0 = rg[head * GN + gr0];
    const float rv1 = rg[head * GN + gr1];
    const unsigned long long* adjr0 = adjb + (size_t)gr0 * 64 + jt0;
    const unsigned long long* adjr1 = adjb + (size_t)gr1 * 64 + jt0;
    // eb uint4 stream: tile t, ks k, quad q -> ebq4[t*16 + k*8 + q*2 + {0,1}]
    const uint4* ebq4 = (const uint4*)(ebg + (size_t)head * (GN / 2)) + (jb >> 2) + quad * 2;

    const _Float16 rh0 = (_Float16)rv0, rh1 = (_Float16)rv1;
    const f16x2 rv2_0 = {rh0, rh0};
    const f16x2 rv2_1 = {rh1, rh1};

    f32x4 acc0[4] = {}, acc1[4] = {};
    f32x4 accd0 = {}, accd1 = {};
    union { unsigned u[4]; f16x8 v; } ones;
    #pragma unroll
    for (int q = 0; q < 4; ++q) ones.u[q] = 0x3C003C00u;   // fp16 1.0 x8

    // stage tiles T..T+3 (contiguous 32 KB in imgh) into hb[buf]; 256 thr
    #define STAGE4(buf, T)                                                                 \
        do {                                                                               \
            const unsigned short* gh_ = ih + (size_t)(T) * 4096;                           \
            _Pragma("unroll")                                                              \
            for (int c_ = 0; c_ < 8; ++c_)                                                 \
                __builtin_amdgcn_global_load_lds(                                          \
                    (const __attribute__((address_space(1))) unsigned int*)(gh_ + c_ * 2048 + tid * 8), \
                    (__attribute__((address_space(3))) unsigned int*)&hb[buf][c_ * 2048 + tid * 8],     \
                    16, 0, 0);                                                             \
        } while (0)

    // build one group's packed weights for a ks slice
    #define WPACK(WFR, BITS, RV2)                                                          \
        do {                                                                               \
            _Pragma("unroll")                                                              \
            for (int p = 0; p < 4; ++p) {                                                  \
                const unsigned lo = (unsigned)(((int)((BITS) << (31 - 2 * p))) >> 31);     \
                const unsigned hi = (unsigned)(((int)((BITS) << (30 - 2 * p))) >> 31);     \
                const unsigned msk = MASK_PERM(hi, lo);                                    \
                union { unsigned u; f16x2 h; } B2, b2, w;                                  \
                B2.u = Bw[p]; b2.u = bw[p];                                                \
                w.h = __builtin_elementwise_max((RV2) * B2.h, b2.h);                       \
                (WFR).u[p] = w.u & msk;                                                    \
            }                                                                              \
        } while (0)

    // one j-tile: bh read ONCE per ks, both groups' pack+5 MFMA
    #define CTILE(cur, half, WD0, WD1, A0, A1, B0, B1)                                     \
        do {                                                                               \
            _Pragma("unroll")                                                              \
            for (int ks = 0; ks < 2; ++ks) {                                               \
                const unsigned bits0 = (unsigned)((WD0) >> (ks * 32 + quad * 8)) & 0xFFu;  \
                const unsigned bits1 = (unsigned)((WD1) >> (ks * 32 + quad * 8)) & 0xFFu;  \
                const uint4 ua = ks ? (B0) : (A0);                                         \
                const uint4 ub = ks ? (B1) : (A1);                                         \
                const unsigned Bw[4] = {ua.x, ua.z, ub.x, ub.z};                           \
                const unsigned bw[4] = {ua.y, ua.w, ub.y, ub.w};                           \
                f16x8 bhf[4];                                                              \
                _Pragma("unroll")                                                          \
                for (int nt = 0; nt < 4; ++nt) {                                           \
                    const int f = nt * 16 + row;                                           \
                    const int off = (half) * 4096 + f * 64 + (((ks * 4 + quad) ^ (f & 7)) * 8); \
                    bhf[nt] = *(const f16x8*)&hb[cur][off];                                \
                }                                                                          \
                union { unsigned u[4]; f16x8 v; } wfr0, wfr1;                              \
                WPACK(wfr0, bits0, rv2_0);                                                 \
                __builtin_amdgcn_s_setprio(1);                                             \
                accd0 = __builtin_amdgcn_mfma_f32_16x16x32_f16(wfr0.v, ones.v, accd0, 0, 0, 0); \
                _Pragma("unroll")                                                          \
                for (int nt = 0; nt < 4; ++nt)                                             \
                    acc0[nt] = __builtin_amdgcn_mfma_f32_16x16x32_f16(wfr0.v, bhf[nt], acc0[nt], 0, 0, 0); \
                WPACK(wfr1, bits1, rv2_1);                                                 \
                accd1 = __builtin_amdgcn_mfma_f32_16x16x32_f16(wfr1.v, ones.v, accd1, 0, 0, 0); \
                _Pragma("unroll")                                                          \
                for (int nt = 0; nt < 4; ++nt)                                             \
                    acc1[nt] = __builtin_amdgcn_mfma_f32_16x16x32_f16(wfr1.v, bhf[nt], acc1[nt], 0, 0, 0); \
                __builtin_amdgcn_s_setprio(0);                                             \
            }                                                                              \
        } while (0)

    STAGE4(0, jt0);
    // ---- prologue prefetch of tile 0 scalars (covered by first barrier) ----
    unsigned long long wdn0 = adjr0[0], wdn1 = adjr1[0];
    uint4 nA0 = ebq4[0], nA1 = ebq4[1], nB0 = ebq4[8], nB1 = ebq4[9];

    #pragma unroll 1
    for (int ph = 0; ph < njp4; ++ph) {
        __syncthreads();                             // drains stage+scalars for this phase
        const int cur = ph & 1;
        if (ph + 1 < njp4) STAGE4(cur ^ 1, jt0 + 4 * (ph + 1));
        #pragma unroll
        for (int q = 0; q < 4; ++q) {                // 4 tiles per phase
            const int t = 4 * ph + q;
            const unsigned long long wd0 = wdn0, wd1 = wdn1;
            const uint4 a0 = nA0, a1 = nA1, b0 = nB0, b1 = nB1;
            if (t + 1 < njt) {                       // prefetch next tile scalars
                const int tn = t + 1;
                wdn0 = adjr0[tn]; wdn1 = adjr1[tn];
                nA0 = ebq4[tn * 16];     nA1 = ebq4[tn * 16 + 1];
                nB0 = ebq4[tn * 16 + 8]; nB1 = ebq4[tn * 16 + 9];
            }
            CTILE(cur, q, wd0, wd1, a0, a1, b0, b1);
        }
    }
    #undef STAGE4
    #undef WPACK
    #undef CTILE

    float* o = pO + (size_t)slice * (GN * 64);
    #pragma unroll
    for (int r = 0; r < 4; ++r) {
        const int grow0 = i0 + wv * 16 + quad * 4 + r;
        #pragma unroll
        for (int nt = 0; nt < 4; ++nt)
            __builtin_nontemporal_store(acc0[nt][r], &o[(size_t)grow0 * 64 + nt * 16 + row]);
        const int grow1 = grow0 + 64;
        #pragma unroll
        for (int nt = 0; nt < 4; ++nt)
            __builtin_nontemporal_store(acc1[nt][r], &o[(size_t)grow1 * 64 + nt * 16 + row]);
    }
    // accd: D[i][j] = den_i (cols identical since B==1); C/D row = quad*4+r
    if (row == 0) {
        #pragma unroll
        for (int r = 0; r < 4; ++r) {
            pd[slice * GN + i0 + wv * 16 + quad * 4 + r] = accd0[r];
            pd[slice * GN + i0 + 64 + wv * 16 + quad * 4 + r] = accd1[r];
        }
    }
}

// Fused zred + l2prep, 16 rows/block (256 blocks): combine 2-chunk L1
// partials -> z (LDS) -> h2 = z @ W_out -> row factors + fp16 image.
__global__ __launch_bounds__(256) void mid(const float* __restrict__ pO,
                                           const float* __restrict__ pd,
                                           const float* __restrict__ Wo,
                                           const float* __restrict__ ao,
                                           unsigned short* __restrict__ img2h,
                                           float* __restrict__ rbL,
                                           uint2* __restrict__ eb2L) {
    __shared__ __align__(16) float zt[16][68];
    __shared__ float Wl[64 * 57];
    __shared__ float invd[8][16];
    const int tid = threadIdx.x;
    const int i0 = blockIdx.x * 16;
    for (int idx = tid; idx < 64 * 56; idx += 256) {
        int k = idx / 56, c = idx - k * 56;
        Wl[k * 57 + c] = Wo[idx];
    }
    if (tid < 128) {
        int hd = tid >> 4, r = tid & 15;
        invd[hd][r] = 1.f / (pd[(2 * hd) * GN + i0 + r] + pd[(2 * hd + 1) * GN + i0 + r]);
    }
    __syncthreads();
    #pragma unroll
    for (int it = 0; it < 4; ++it) {                 // z fill: 16x64 elems
        int e = it * 256 + tid;
        int r = e >> 6, f = e & 63;
        size_t base = (size_t)(i0 + r) * 64 + f;
        float s = 0.f;
        #pragma unroll
        for (int hd = 0; hd < GNH; ++hd) {
            float o = pO[(size_t)(2 * hd) * (GN * 64) + base] +
                      pO[(size_t)(2 * hd + 1) * (GN * 64) + base];
            float v = o * invd[hd][r];
            s += v > 0.f ? v : FAST_EXP2(v * LOG2E) - 1.f;
        }
        zt[r][f] = s * 0.125f;
    }
    __syncthreads();
    const int rrow = tid >> 4, cseg = (tid & 15) * 4;
    float hreg[4] = {0.f, 0.f, 0.f, 0.f};
    for (int k0 = 0; k0 < 64; k0 += 4) {
        float4 zv = *(const float4*)&zt[rrow][k0];
        #pragma unroll
        for (int c = 0; c < 4; ++c) {
            int col = cseg + c;
            if (col < 56)
                hreg[c] += zv.x * Wl[k0 * 57 + col] + zv.y * Wl[(k0 + 1) * 57 + col] +
                           zv.z * Wl[(k0 + 2) * 57 + col] + zv.w * Wl[(k0 + 3) * 57 + col];
        }
    }
    {   // row factors for L2 attention (packed fp16 pairs)
        float p1 = 0.f, p2 = 0.f;
        #pragma unroll
        for (int c = 0; c < 4; ++c) {
            int col = cseg + c;
            if (col < 56) {
                p1 += hreg[c] * ao[col];
                p2 += hreg[c] * ao[56 + col];
            }
        }
        p1 += __shfl_xor(p1, 1); p1 += __shfl_xor(p1, 2);
        p1 += __shfl_xor(p1, 4); p1 += __shfl_xor(p1, 8);
        p2 += __shfl_xor(p2, 1); p2 += __shfl_xor(p2, 2);
        p2 += __shfl_xor(p2, 4); p2 += __shfl_xor(p2, 8);
        // all lanes hold full p1,p2 for row rrow = tid>>4
        const float r_ = FAST_EXP2(0.8f * p1 * LOG2E);
        const float B_ = FAST_EXP2(p2 * LOG2E);
        const float b_ = FAST_EXP2(0.2f * p2 * LOG2E);
        const float Bo = __shfl_xor(B_, 16);         // row rrow^1's B
        const float bo = __shfl_xor(b_, 16);
        if ((tid & 15) == 0) rbL[i0 + rrow] = r_;
        if ((tid & 31) == 0) {                       // even rrow writes the pair
            uint2 e;
            e.x = pk_f16(B_, Bo);
            e.y = pk_f16(b_, bo);
            eb2L[(i0 + rrow) >> 1] = e;
        }
    }
    __syncthreads();
    #pragma unroll
    for (int c = 0; c < 4; ++c) zt[rrow][cseg + c] = (cseg + c < 56) ? hreg[c] : 0.f;
    __syncthreads();
    if (tid < 128) {                                 // img emit: 64 f x 2 c-units (fp16)
        const int jt = i0 >> 6;
        const int cbase = (i0 & 63) >> 3;
        const int f = tid >> 1, c = cbase + (tid & 1);
        const int lr = (tid & 1) * 8;
        unsigned hp[4];
        #pragma unroll
        for (int pp = 0; pp < 4; ++pp)
            hp[pp] = pk_f16(zt[lr + 2 * pp][f], zt[lr + 2 * pp + 1][f]);
        size_t base = (size_t)jt * 4096 + f * 64 + ((c ^ (f & 7)) * 8);
        *(uint4*)&img2h[base] = *(uint4*)hp;
    }
}

// combine NCH j-chunk partials, /denom, elu, softmax(56) -> out
template <int NCH>
__global__ __launch_bounds__(256) void fink2(const float* __restrict__ pO,
                                             const float* __restrict__ pd,
                                             float* __restrict__ out) {
    const int lane = threadIdx.x & 63;
    const int w = threadIdx.x >> 6;
    const int i = blockIdx.x * 4 + w;
    float o = 0.f, d = 0.f;
    #pragma unroll
    for (int c = 0; c < NCH; ++c) d += pd[c * GN + i];
    if (lane < 56) {
        #pragma unroll
        for (int c = 0; c < NCH; ++c) o += pO[(size_t)c * (GN * 64) + (size_t)i * 64 + lane];
    }
    float v = -1e30f;
    if (lane < 56) {
        float t = o / d;
        v = t > 0.f ? t : expm1f(t);
    }
    float m = v;
    #pragma unroll
    for (int off = 32; off; off >>= 1) m = fmaxf(m, __shfl_down(m, off));
    m = __shfl(m, 0);
    float p = (lane < 56) ? __expf(v - m) : 0.f;
    float s = p;
    #pragma unroll
    for (int off = 32; off; off >>= 1) s += __shfl_down(s, off);
    s = __shfl(s, 0);
    if (lane < 56) out[(size_t)i * 56 + lane] = p / s;
}

extern "C" void kernel_launch(void* const* d_in, const int* in_sizes, int n_in,
                              void* d_out, int out_size, void* d_ws, size_t ws_size,
                              hipStream_t stream) {
    const float* x    = (const float*)d_in[0];
    const int*   adj  = (const int*)d_in[1];
    const float* Ws   = (const float*)d_in[2];
    const float* As   = (const float*)d_in[3];
    const float* Wo   = (const float*)d_in[4];
    const float* ao   = (const float*)d_in[5];
    float* out = (float*)d_out;

    char* ws = (char*)d_ws;
    unsigned long long* adjb = (unsigned long long*)(ws + 0);           // [0, 2097152)
    unsigned short* img1h = (unsigned short*)(ws + 2097152);            // [2097152, 6291456)
    float* pO    = (float*)(ws + 6291456);                              // [6291456, 23068672) 16 slices
    unsigned short* x_hi = (unsigned short*)(ws + 6291456);             // alias pO (pre-gemm only)
    float* pd    = (float*)(ws + 23068672);                             // [23068672, 23330816)
    float* rL    = (float*)(ws + 23330816);                             // [23330816, 23461888)
    uint2* ebL   = (uint2*)(ws + 23461888);                             // [23461888, 23724032) 8B/j-pair*2048*8
    float* rbL   = (float*)(ws + 23724032);                             // [23724032, 23740416)
    uint2* eb2L  = (uint2*)(ws + 23740416);                             // [23740416, 23756800) 2048*8B
    unsigned short* img2h = (unsigned short*)(ws + 23773184);           // [23773184, 24297472)
    unsigned short* WT_hi = (unsigned short*)(ws + 24297472);           // [24297472, 24821760)
    // total ~24.82 MB, no overlaps

    prep<<<2624, 256, 0, stream>>>(adj, x, Ws, adjb, x_hi, WT_hi);
    gemm_fused<<<dim3(8, 64), 256, 0, stream>>>(x_hi, WT_hi, As, img1h, rL, ebL);
    attn15<2><<<dim3(32, 16), 256, 0, stream>>>(img1h, rL, ebL, adjb, pO, pd);
    mid<<<256, 256, 0, stream>>>(pO, pd, Wo, ao, img2h, rbL, eb2L);
    attn15<8><<<dim3(32, 8), 256, 0, stream>>>(img2h, rbL, eb2L, adjb, pO, pd);
    fink2<8><<<1024, 256, 0, stream>>>(pO, pd, out);
}

// Round 18
// 175.078 us; speedup vs baseline: 1.0219x; 1.0219x over previous
//
#include <hip/hip_runtime.h>
#include <hip/hip_bf16.h>
#include <math.h>

// GAT forward, N=4096, nfeat=512, nhid=64, nheads=8, nout=56, f32 in/out.
// R33 = REVERT TO R29 (session best, 175.7us). Post-R29 experiments all
// confirmed-negative and removed:
//   R30: XCD remap @ NCHUNK=1 -> 190.7 (occupancy collapse)
//   R31: XCD remap @ NCHUNK=2 -> 178.1 (FETCH cut buys no time; hidden)
//   R32: non-temporal pO stores -> 178.9 (write stream to HBM latency)
// R29 config: prep grid-stride 2624 | gemm 2-kt-phase 64KB LDS | attn-L1
// NCHUNK=2 standard mapping + setprio | attn-L2 NCHUNK=8 | fink2<8> |
// mid 2-slice combine. Session: 205.8 -> 175.7us via multiplicative
// softmax (zero-transcendental attn), fp16 pk-math pipeline, ones-MFMA
// den, barrier-phase amortization, scalar prefetch, grid-stride prep.

#define GN 4096
#define GNH 8
#define LOG2E 1.4426950408889634f

typedef _Float16 f16x8 __attribute__((ext_vector_type(8)));
typedef _Float16 f16x2 __attribute__((ext_vector_type(2)));
typedef __fp16 fp16x2_raw __attribute__((ext_vector_type(2)));
typedef float f32x4 __attribute__((ext_vector_type(4)));

#if defined(__has_builtin)
#if __has_builtin(__builtin_amdgcn_exp2f)
#define FAST_EXP2(x) __builtin_amdgcn_exp2f(x)
#endif
#if __has_builtin(__builtin_amdgcn_perm)
#define MASK_PERM(h, l) __builtin_amdgcn_perm((h), (l), 0x05040100u)
#endif
#if __has_builtin(__builtin_amdgcn_cvt_pkrtz)
#define HAVE_PKRTZ 1
#endif
#endif
#ifndef FAST_EXP2
#define FAST_EXP2(x) __expf((x)*0.6931471805599453f)
#endif
#ifndef MASK_PERM
#define MASK_PERM(h, l) (((h) & 0xFFFF0000u) | ((l) & 0xFFFFu))
#endif

// pack two floats to fp16 pair (a in low 16, b in high 16)
__device__ inline unsigned pk_f16(float a, float b) {
#ifdef HAVE_PKRTZ
    union { fp16x2_raw h; unsigned u; } r;
    r.h = __builtin_amdgcn_cvt_pkrtz(a, b);
    return r.u;
#else
    union { _Float16 h; unsigned short s; } x, y;
    x.h = (_Float16)a; y.h = (_Float16)b;
    return (unsigned)x.s | ((unsigned)y.s << 16);
#endif
}

// Fused prep (grid-stride, 2624 blocks):
//  [0,2048)      pack_adj  x8 iters (bitmask)
//  [2048,2560)   conv_x    x2 iters -> swizzled x image (fp16)
//  [2560,2624)   conv_wt   -> swizzled W^T image (fp16), tiles [head*8+kt]
// Image unit (m, c) at shorts offset m*64 + ((c^(m&7))*8), elems k = c*8+q.
__global__ __launch_bounds__(256) void prep(const int* __restrict__ adj,
                                            const float* __restrict__ x,
                                            const float* __restrict__ Ws,
                                            unsigned long long* __restrict__ adjb,
                                            unsigned short* __restrict__ xh,
                                            unsigned short* __restrict__ wth) {
    const int b = blockIdx.x;
    const int tid = threadIdx.x;
    if (b < 2048) {
        const int wv = tid >> 6, lane = tid & 63;
        #pragma unroll 1
        for (int it = 0; it < 8; ++it) {
            const int ob = b * 8 + it;
            const size_t ebase = ((size_t)ob * 4 + wv) * 256;
            unsigned long long m[4];
            #pragma unroll
            for (int e = 0; e < 4; ++e)
                m[e] = __ballot(adj[ebase + e * 64 + lane] > 0);
            if (lane == 0) {
                #pragma unroll
                for (int e = 0; e < 4; ++e) adjb[(ebase >> 6) + e] = m[e];
            }
        }
    } else if (b < 2560) {
        #pragma unroll 1
        for (int it = 0; it < 2; ++it) {
            int gid = ((b - 2048) * 2 + it) * 256 + tid;  // over 4096 rows x 64 units
            int i = gid >> 6, c64 = gid & 63;
            const float* xp = x + (size_t)i * 512 + c64 * 8;
            float4 a = *(const float4*)xp;
            float4 v = *(const float4*)(xp + 4);
            unsigned hp[4];
            hp[0] = pk_f16(a.x, a.y);
            hp[1] = pk_f16(a.z, a.w);
            hp[2] = pk_f16(v.x, v.y);
            hp[3] = pk_f16(v.z, v.w);
            int il = i & 63, kt = c64 >> 3, c = c64 & 7;
            size_t base = ((size_t)(i >> 6) * 8 + kt) * 4096 + il * 64 + ((c ^ (il & 7)) * 8);
            *(uint4*)&xh[base] = *(uint4*)hp;
        }
    } else {
        __shared__ float t[64][65];
        int b2 = b - 2560;                           // head*8 + kt
        int head = b2 >> 3, k0 = (b2 & 7) * 64;
        #pragma unroll
        for (int it = 0; it < 4; ++it) {
            int e = (tid + it * 256) * 4;            // over 64k x 64f
            int kl = e >> 6, f4 = e & 63;
            float4 v = *(const float4*)&Ws[((size_t)head * 512 + k0 + kl) * 64 + f4];
            t[f4 + 0][kl] = v.x; t[f4 + 1][kl] = v.y;
            t[f4 + 2][kl] = v.z; t[f4 + 3][kl] = v.w;
        }
        __syncthreads();
        int f = tid >> 2;
        #pragma unroll
        for (int p = 0; p < 2; ++p) {
            int c = (tid & 3) * 2 + p;
            unsigned hp[4];
            #pragma unroll
            for (int pp = 0; pp < 4; ++pp)
                hp[pp] = pk_f16(t[f][c * 8 + 2 * pp], t[f][c * 8 + 2 * pp + 1]);
            size_t base = (size_t)b2 * 4096 + f * 64 + ((c ^ (f & 7)) * 8);
            *(uint4*)&wth[base] = *(uint4*)hp;
        }
    }
}

// h = x @ W (single fp16 product). TWO k-tiles per barrier phase
// (4 phases), lds = 2 bufs x 2 kt x {x,w} x 8KB = 64 KB, 2 blk/CU.
// Epilogue emits fp16 swizzled h image + per-row softmax factors:
// rL = exp(.8*s1) f32; ebL = packed fp16 pairs {B_{2j},B_{2j+1}},{b_..}.
// grid (8 heads, 64 itiles).
__global__ __launch_bounds__(256, 2) void gemm_fused(const unsigned short* __restrict__ xh,
                                                     const unsigned short* __restrict__ wth,
                                                     const float* __restrict__ As,
                                                     unsigned short* __restrict__ imgh,
                                                     float* __restrict__ rL,
                                                     uint2* __restrict__ ebL) {
    __shared__ __align__(16) unsigned short lds[2][2][2][4096];  // 64 KB: [buf][kt][x,w]
    const int tid = threadIdx.x;
    const int head = blockIdx.x;
    const int itile = blockIdx.y;
    const int i0 = itile * 64;
    const unsigned short* srcs[2] = {xh + (size_t)itile * 8 * 4096,
                                     wth + (size_t)head * 8 * 4096};
    const int lane = tid & 63, wv_ = tid >> 6;
    const int mi = (wv_ & 1) * 32, fi = (wv_ >> 1) * 32;
    const int row = lane & 15, quad = lane >> 4;
    f32x4 acc[2][2] = {};

    // stage k-tiles 2*kp and 2*kp+1 (both operands) into lds[buf]
    #define GSTAGE2(buf, kp)                                                               \
        do {                                                                               \
            _Pragma("unroll")                                                              \
            for (int tk_ = 0; tk_ < 2; ++tk_) {                                            \
                _Pragma("unroll")                                                          \
                for (int q_ = 0; q_ < 2; ++q_) {                                           \
                    const unsigned short* s_ = srcs[q_] + (size_t)((kp) * 2 + tk_) * 4096; \
                    _Pragma("unroll")                                                      \
                    for (int c_ = 0; c_ < 2; ++c_)                                         \
                        __builtin_amdgcn_global_load_lds(                                  \
                            (const __attribute__((address_space(1))) unsigned int*)(s_ + c_ * 2048 + tid * 8), \
                            (__attribute__((address_space(3))) unsigned int*)&lds[buf][tk_][q_][c_ * 2048 + tid * 8], \
                            16, 0, 0);                                                     \
                }                                                                          \
            }                                                                              \
        } while (0)

    GSTAGE2(0, 0);
    for (int kp = 0; kp < 4; ++kp) {
        __syncthreads();                             // drains loads into buf cur
        const int cur = kp & 1;
        if (kp + 1 < 4) GSTAGE2(cur ^ 1, kp + 1);
        #pragma unroll
        for (int tki = 0; tki < 2; ++tki) {
            #pragma unroll
            for (int ks = 0; ks < 2; ++ks) {
                f16x8 ah[2], bh[2];
                #pragma unroll
                for (int t = 0; t < 2; ++t) {
                    const int m_ = mi + t * 16 + row;
                    const int offa = m_ * 64 + (((ks * 4 + quad) ^ (m_ & 7)) * 8);
                    ah[t] = *(const f16x8*)&lds[cur][tki][0][offa];
                    const int f_ = fi + t * 16 + row;
                    const int offb = f_ * 64 + (((ks * 4 + quad) ^ (f_ & 7)) * 8);
                    bh[t] = *(const f16x8*)&lds[cur][tki][1][offb];
                }
                #pragma unroll
                for (int mt = 0; mt < 2; ++mt)
                    #pragma unroll
                    for (int nt = 0; nt < 2; ++nt)
                        acc[mt][nt] = __builtin_amdgcn_mfma_f32_16x16x32_f16(ah[mt], bh[nt], acc[mt][nt], 0, 0, 0);
            }
        }
    }
    #undef GSTAGE2
    // ---- fused epilogue ----
    __syncthreads();
    float* ht = (float*)&lds[0][0][0][0];            // 64 x 68 f32 (17.4 KB <= 64 KB)
    #pragma unroll
    for (int mt = 0; mt < 2; ++mt)
        #pragma unroll
        for (int nt = 0; nt < 2; ++nt)
            #pragma unroll
            for (int r = 0; r < 4; ++r)
                ht[(mi + mt * 16 + quad * 4 + r) * 68 + fi + nt * 16 + row] = acc[mt][nt][r];
    __syncthreads();
    {   // s1/s2 -> row factors: thread t -> row t>>2, seg (t&3)*16
        const int rrow = tid >> 2, seg = (tid & 3) * 16;
        const float* ah = As + head * 128;
        float p1 = 0.f, p2 = 0.f;
        #pragma unroll
        for (int c = 0; c < 16; ++c) {
            float v = ht[rrow * 68 + seg + c];
            p1 += v * ah[seg + c];
            p2 += v * ah[64 + seg + c];
        }
        p1 += __shfl_xor(p1, 1); p1 += __shfl_xor(p1, 2);
        p2 += __shfl_xor(p2, 1); p2 += __shfl_xor(p2, 2);
        // all lanes now hold full p1,p2 for row rrow
        const float r_ = FAST_EXP2(0.8f * p1 * LOG2E);
        const float B_ = FAST_EXP2(p2 * LOG2E);
        const float b_ = FAST_EXP2(0.2f * p2 * LOG2E);
        const float Bo = __shfl_xor(B_, 4);          // row rrow^1's B
        const float bo = __shfl_xor(b_, 4);
        const int gi = i0 + rrow;
        if ((tid & 3) == 0) rL[head * GN + gi] = r_;
        if ((tid & 7) == 0) {                        // even rrow writes the pair
            uint2 e;
            e.x = pk_f16(B_, Bo);
            e.y = pk_f16(b_, bo);
            ebL[head * (GN / 2) + (gi >> 1)] = e;
        }
    }
    {   // swizzled image emit (fp16)
        const int f = tid >> 2;
        size_t base = ((size_t)head * 64 + itile) * 4096 + (size_t)f * 64;
        #pragma unroll
        for (int p = 0; p < 2; ++p) {
            int c = (tid & 3) * 2 + p;
            unsigned hp[4];
            #pragma unroll
            for (int pp = 0; pp < 4; ++pp)
                hp[pp] = pk_f16(ht[(c * 8 + 2 * pp) * 68 + f], ht[(c * 8 + 2 * pp + 1) * 68 + f]);
            int off = (c ^ (f & 7)) * 8;
            *(uint4*)&imgh[base + off] = *(uint4*)hp;
        }
    }
}

// Fused masked-softmax attention, MULTIPLICATIVE fp16-packed weights:
// w'_pair = pk_max(pk_mul(rv2, B2), b2) & signext-bit-mask; den = ones-MFMA
// on the SAME packed values. 4 waves x 2 ROW-GROUPS x 16 rows = 128
// rows/block; FOUR j-tiles per barrier phase (hb = 2 bufs x 4 tiles =
// 64 KB; 2 blk/CU). s_setprio(1) around each tile's MFMA cluster.
// grid (32, GNH*NCHUNK) or (32, NCHUNK) for L2.
template <int NCHUNK>
__global__ __launch_bounds__(256, 2) void attn15(const unsigned short* __restrict__ imgh,
                                                 const float* __restrict__ rg,
                                                 const uint2* __restrict__ ebg,
                                                 const unsigned long long* __restrict__ adjb,
                                                 float* __restrict__ pO,
                                                 float* __restrict__ pd) {
    __shared__ __align__(16) unsigned short hb[2][16384];  // 64 KB: [buf][4 tiles]
    const int tid = threadIdx.x;
    const int lane = tid & 63, wv = tid >> 6;              // wv in [0,4)
    const int row = lane & 15, quad = lane >> 4;
    const int head = blockIdx.y / NCHUNK;
    const int chunk = blockIdx.y % NCHUNK;
    const int ib = blockIdx.x;
    const int slice = blockIdx.y;
    const int i0 = ib * 128;                               // 128 rows/block
    const int jb = chunk * (GN / NCHUNK);
    const int njt = (GN / NCHUNK) / 64;
    const int njp4 = njt >> 2;                       // 4 tiles per phase
    const int jt0 = jb >> 6;
    const unsigned short* ih = imgh + (size_t)head * (64 * GN);
    const int gr0 = i0 + wv * 16 + row;                    // group 0 row
    const int gr1 = gr0 + 64;                              // group 1 row
    const float rv0 = rg[head * GN + gr0];
    const float rv1 = rg[head * GN + gr1];
    const unsigned long long* adjr0 = adjb + (size_t)gr0 * 64 + jt0;
    const unsigned long long* adjr1 = adjb + (size_t)gr1 * 64 + jt0;
    // eb uint4 stream: tile t, ks k, quad q -> ebq4[t*16 + k*8 + q*2 + {0,1}]
    const uint4* ebq4 = (const uint4*)(ebg + (size_t)head * (GN / 2)) + (jb >> 2) + quad * 2;

    const _Float16 rh0 = (_Float16)rv0, rh1 = (_Float16)rv1;
    const f16x2 rv2_0 = {rh0, rh0};
    const f16x2 rv2_1 = {rh1, rh1};

    f32x4 acc0[4] = {}, acc1[4] = {};
    f32x4 accd0 = {}, accd1 = {};
    union { unsigned u[4]; f16x8 v; } ones;
    #pragma unroll
    for (int q = 0; q < 4; ++q) ones.u[q] = 0x3C003C00u;   // fp16 1.0 x8

    // stage tiles T..T+3 (contiguous 32 KB in imgh) into hb[buf]; 256 thr
    #define STAGE4(buf, T)                                                                 \
        do {                                                                               \
            const unsigned short* gh_ = ih + (size_t)(T) * 4096;                           \
            _Pragma("unroll")                                                              \
            for (int c_ = 0; c_ < 8; ++c_)                                                 \
                __builtin_amdgcn_global_load_lds(                                          \
                    (const __attribute__((address_space(1))) unsigned int*)(gh_ + c_ * 2048 + tid * 8), \
                    (__attribute__((address_space(3))) unsigned int*)&hb[buf][c_ * 2048 + tid * 8],     \
                    16, 0, 0);                                                             \
        } while (0)

    // build one group's packed weights for a ks slice
    #define WPACK(WFR, BITS, RV2)                                                          \
        do {                                                                               \
            _Pragma("unroll")                                                              \
            for (int p = 0; p < 4; ++p) {                                                  \
                const unsigned lo = (unsigned)(((int)((BITS) << (31 - 2 * p))) >> 31);     \
                const unsigned hi = (unsigned)(((int)((BITS) << (30 - 2 * p))) >> 31);     \
                const unsigned msk = MASK_PERM(hi, lo);                                    \
                union { unsigned u; f16x2 h; } B2, b2, w;                                  \
                B2.u = Bw[p]; b2.u = bw[p];                                                \
                w.h = __builtin_elementwise_max((RV2) * B2.h, b2.h);                       \
                (WFR).u[p] = w.u & msk;                                                    \
            }                                                                              \
        } while (0)

    // one j-tile: bh read ONCE per ks, both groups' pack+5 MFMA
    #define CTILE(cur, half, WD0, WD1, A0, A1, B0, B1)                                     \
        do {                                                                               \
            _Pragma("unroll")                                                              \
            for (int ks = 0; ks < 2; ++ks) {                                               \
                const unsigned bits0 = (unsigned)((WD0) >> (ks * 32 + quad * 8)) & 0xFFu;  \
                const unsigned bits1 = (unsigned)((WD1) >> (ks * 32 + quad * 8)) & 0xFFu;  \
                const uint4 ua = ks ? (B0) : (A0);                                         \
                const uint4 ub = ks ? (B1) : (A1);                                         \
                const unsigned Bw[4] = {ua.x, ua.z, ub.x, ub.z};                           \
                const unsigned bw[4] = {ua.y, ua.w, ub.y, ub.w};                           \
                f16x8 bhf[4];                                                              \
                _Pragma("unroll")                                                          \
                for (int nt = 0; nt < 4; ++nt) {                                           \
                    const int f = nt * 16 + row;                                           \
                    const int off = (half) * 4096 + f * 64 + (((ks * 4 + quad) ^ (f & 7)) * 8); \
                    bhf[nt] = *(const f16x8*)&hb[cur][off];                                \
                }                                                                          \
                union { unsigned u[4]; f16x8 v; } wfr0, wfr1;                              \
                WPACK(wfr0, bits0, rv2_0);                                                 \
                __builtin_amdgcn_s_setprio(1);                                             \
                accd0 = __builtin_amdgcn_mfma_f32_16x16x32_f16(wfr0.v, ones.v, accd0, 0, 0, 0); \
                _Pragma("unroll")                                                          \
                for (int nt = 0; nt < 4; ++nt)                                             \
                    acc0[nt] = __builtin_amdgcn_mfma_f32_16x16x32_f16(wfr0.v, bhf[nt], acc0[nt], 0, 0, 0); \
                WPACK(wfr1, bits1, rv2_1);                                                 \
                accd1 = __builtin_amdgcn_mfma_f32_16x16x32_f16(wfr1.v, ones.v, accd1, 0, 0, 0); \
                _Pragma("unroll")                                                          \
                for (int nt = 0; nt < 4; ++nt)                                             \
                    acc1[nt] = __builtin_amdgcn_mfma_f32_16x16x32_f16(wfr1.v, bhf[nt], acc1[nt], 0, 0, 0); \
                __builtin_amdgcn_s_setprio(0);                                             \
            }                                                                              \
        } while (0)

    STAGE4(0, jt0);
    // ---- prologue prefetch of tile 0 scalars (covered by first barrier) ----
    unsigned long long wdn0 = adjr0[0], wdn1 = adjr1[0];
    uint4 nA0 = ebq4[0], nA1 = ebq4[1], nB0 = ebq4[8], nB1 = ebq4[9];

    #pragma unroll 1
    for (int ph = 0; ph < njp4; ++ph) {
        __syncthreads();                             // drains stage+scalars for this phase
        const int cur = ph & 1;
        if (ph + 1 < njp4) STAGE4(cur ^ 1, jt0 + 4 * (ph + 1));
        #pragma unroll
        for (int q = 0; q < 4; ++q) {                // 4 tiles per phase
            const int t = 4 * ph + q;
            const unsigned long long wd0 = wdn0, wd1 = wdn1;
            const uint4 a0 = nA0, a1 = nA1, b0 = nB0, b1 = nB1;
            if (t + 1 < njt) {                       // prefetch next tile scalars
                const int tn = t + 1;
                wdn0 = adjr0[tn]; wdn1 = adjr1[tn];
                nA0 = ebq4[tn * 16];     nA1 = ebq4[tn * 16 + 1];
                nB0 = ebq4[tn * 16 + 8]; nB1 = ebq4[tn * 16 + 9];
            }
            CTILE(cur, q, wd0, wd1, a0, a1, b0, b1);
        }
    }
    #undef STAGE4
    #undef WPACK
    #undef CTILE

    float* o = pO + (size_t)slice * (GN * 64);
    #pragma unroll
    for (int r = 0; r < 4; ++r) {
        const int grow0 = i0 + wv * 16 + quad * 4 + r;
        #pragma unroll
        for (int nt = 0; nt < 4; ++nt)
            o[(size_t)grow0 * 64 + nt * 16 + row] = acc0[nt][r];
        const int grow1 = grow0 + 64;
        #pragma unroll
        for (int nt = 0; nt < 4; ++nt)
            o[(size_t)grow1 * 64 + nt * 16 + row] = acc1[nt][r];
    }
    // accd: D[i][j] = den_i (cols identical since B==1); C/D row = quad*4+r
    if (row == 0) {
        #pragma unroll
        for (int r = 0; r < 4; ++r) {
            pd[slice * GN + i0 + wv * 16 + quad * 4 + r] = accd0[r];
            pd[slice * GN + i0 + 64 + wv * 16 + quad * 4 + r] = accd1[r];
        }
    }
}

// Fused zred + l2prep, 16 rows/block (256 blocks): combine 2-chunk L1
// partials -> z (LDS) -> h2 = z @ W_out -> row factors + fp16 image.
__global__ __launch_bounds__(256) void mid(const float* __restrict__ pO,
                                           const float* __restrict__ pd,
                                           const float* __restrict__ Wo,
                                           const float* __restrict__ ao,
                                           unsigned short* __restrict__ img2h,
                                           float* __restrict__ rbL,
                                           uint2* __restrict__ eb2L) {
    __shared__ __align__(16) float zt[16][68];
    __shared__ float Wl[64 * 57];
    __shared__ float invd[8][16];
    const int tid = threadIdx.x;
    const int i0 = blockIdx.x * 16;
    for (int idx = tid; idx < 64 * 56; idx += 256) {
        int k = idx / 56, c = idx - k * 56;
        Wl[k * 57 + c] = Wo[idx];
    }
    if (tid < 128) {
        int hd = tid >> 4, r = tid & 15;
        invd[hd][r] = 1.f / (pd[(2 * hd) * GN + i0 + r] + pd[(2 * hd + 1) * GN + i0 + r]);
    }
    __syncthreads();
    #pragma unroll
    for (int it = 0; it < 4; ++it) {                 // z fill: 16x64 elems
        int e = it * 256 + tid;
        int r = e >> 6, f = e & 63;
        size_t base = (size_t)(i0 + r) * 64 + f;
        float s = 0.f;
        #pragma unroll
        for (int hd = 0; hd < GNH; ++hd) {
            float o = pO[(size_t)(2 * hd) * (GN * 64) + base] +
                      pO[(size_t)(2 * hd + 1) * (GN * 64) + base];
            float v = o * invd[hd][r];
            s += v > 0.f ? v : FAST_EXP2(v * LOG2E) - 1.f;
        }
        zt[r][f] = s * 0.125f;
    }
    __syncthreads();
    const int rrow = tid >> 4, cseg = (tid & 15) * 4;
    float hreg[4] = {0.f, 0.f, 0.f, 0.f};
    for (int k0 = 0; k0 < 64; k0 += 4) {
        float4 zv = *(const float4*)&zt[rrow][k0];
        #pragma unroll
        for (int c = 0; c < 4; ++c) {
            int col = cseg + c;
            if (col < 56)
                hreg[c] += zv.x * Wl[k0 * 57 + col] + zv.y * Wl[(k0 + 1) * 57 + col] +
                           zv.z * Wl[(k0 + 2) * 57 + col] + zv.w * Wl[(k0 + 3) * 57 + col];
        }
    }
    {   // row factors for L2 attention (packed fp16 pairs)
        float p1 = 0.f, p2 = 0.f;
        #pragma unroll
        for (int c = 0; c < 4; ++c) {
            int col = cseg + c;
            if (col < 56) {
                p1 += hreg[c] * ao[col];
                p2 += hreg[c] * ao[56 + col];
            }
        }
        p1 += __shfl_xor(p1, 1); p1 += __shfl_xor(p1, 2);
        p1 += __shfl_xor(p1, 4); p1 += __shfl_xor(p1, 8);
        p2 += __shfl_xor(p2, 1); p2 += __shfl_xor(p2, 2);
        p2 += __shfl_xor(p2, 4); p2 += __shfl_xor(p2, 8);
        // all lanes hold full p1,p2 for row rrow = tid>>4
        const float r_ = FAST_EXP2(0.8f * p1 * LOG2E);
        const float B_ = FAST_EXP2(p2 * LOG2E);
        const float b_ = FAST_EXP2(0.2f * p2 * LOG2E);
        const float Bo = __shfl_xor(B_, 16);         // row rrow^1's B
        const float bo = __shfl_xor(b_, 16);
        if ((tid & 15) == 0) rbL[i0 + rrow] = r_;
        if ((tid & 31) == 0) {                       // even rrow writes the pair
            uint2 e;
            e.x = pk_f16(B_, Bo);
            e.y = pk_f16(b_, bo);
            eb2L[(i0 + rrow) >> 1] = e;
        }
    }
    __syncthreads();
    #pragma unroll
    for (int c = 0; c < 4; ++c) zt[rrow][cseg + c] = (cseg + c < 56) ? hreg[c] : 0.f;
    __syncthreads();
    if (tid < 128) {                                 // img emit: 64 f x 2 c-units (fp16)
        const int jt = i0 >> 6;
        const int cbase = (i0 & 63) >> 3;
        const int f = tid >> 1, c = cbase + (tid & 1);
        const int lr = (tid & 1) * 8;
        unsigned hp[4];
        #pragma unroll
        for (int pp = 0; pp < 4; ++pp)
            hp[pp] = pk_f16(zt[lr + 2 * pp][f], zt[lr + 2 * pp + 1][f]);
        size_t base = (size_t)jt * 4096 + f * 64 + ((c ^ (f & 7)) * 8);
        *(uint4*)&img2h[base] = *(uint4*)hp;
    }
}

// combine NCH j-chunk partials, /denom, elu, softmax(56) -> out
template <int NCH>
__global__ __launch_bounds__(256) void fink2(const float* __restrict__ pO,
                                             const float* __restrict__ pd,
                                             float* __restrict__ out) {
    const int lane = threadIdx.x & 63;
    const int w = threadIdx.x >> 6;
    const int i = blockIdx.x * 4 + w;
    float o = 0.f, d = 0.f;
    #pragma unroll
    for (int c = 0; c < NCH; ++c) d += pd[c * GN + i];
    if (lane < 56) {
        #pragma unroll
        for (int c = 0; c < NCH; ++c) o += pO[(size_t)c * (GN * 64) + (size_t)i * 64 + lane];
    }
    float v = -1e30f;
    if (lane < 56) {
        float t = o / d;
        v = t > 0.f ? t : expm1f(t);
    }
    float m = v;
    #pragma unroll
    for (int off = 32; off; off >>= 1) m = fmaxf(m, __shfl_down(m, off));
    m = __shfl(m, 0);
    float p = (lane < 56) ? __expf(v - m) : 0.f;
    float s = p;
    #pragma unroll
    for (int off = 32; off; off >>= 1) s += __shfl_down(s, off);
    s = __shfl(s, 0);
    if (lane < 56) out[(size_t)i * 56 + lane] = p / s;
}

extern "C" void kernel_launch(void* const* d_in, const int* in_sizes, int n_in,
                              void* d_out, int out_size, void* d_ws, size_t ws_size,
                              hipStream_t stream) {
    const float* x    = (const float*)d_in[0];
    const int*   adj  = (const int*)d_in[1];
    const float* Ws   = (const float*)d_in[2];
    const float* As   = (const float*)d_in[3];
    const float* Wo   = (const float*)d_in[4];
    const float* ao   = (const float*)d_in[5];
    float* out = (float*)d_out;

    char* ws = (char*)d_ws;
    unsigned long long* adjb = (unsigned long long*)(ws + 0);           // [0, 2097152)
    unsigned short* img1h = (unsigned short*)(ws + 2097152);            // [2097152, 6291456)
    float* pO    = (float*)(ws + 6291456);                              // [6291456, 23068672) 16 slices
    unsigned short* x_hi = (unsigned short*)(ws + 6291456);             // alias pO (pre-gemm only)
    float* pd    = (float*)(ws + 23068672);                             // [23068672, 23330816)
    float* rL    = (float*)(ws + 23330816);                             // [23330816, 23461888)
    uint2* ebL   = (uint2*)(ws + 23461888);                             // [23461888, 23724032) 8B/j-pair*2048*8
    float* rbL   = (float*)(ws + 23724032);                             // [23724032, 23740416)
    uint2* eb2L  = (uint2*)(ws + 23740416);                             // [23740416, 23756800) 2048*8B
    unsigned short* img2h = (unsigned short*)(ws + 23773184);           // [23773184, 24297472)
    unsigned short* WT_hi = (unsigned short*)(ws + 24297472);           // [24297472, 24821760)
    // total ~24.82 MB, no overlaps

    prep<<<2624, 256, 0, stream>>>(adj, x, Ws, adjb, x_hi, WT_hi);
    gemm_fused<<<dim3(8, 64), 256, 0, stream>>>(x_hi, WT_hi, As, img1h, rL, ebL);
    attn15<2><<<dim3(32, 16), 256, 0, stream>>>(img1h, rL, ebL, adjb, pO, pd);
    mid<<<256, 256, 0, stream>>>(pO, pd, Wo, ao, img2h, rbL, eb2L);
    attn15<8><<<dim3(32, 8), 256, 0, stream>>>(img2h, rbL, eb2L, adjb, pO, pd);
    fink2<8><<<1024, 256, 0, stream>>>(pO, pd, out);
}